// Round 11
// baseline (120.567 us; speedup 1.0000x reference)
//
#include <hip/hip_runtime.h>

// Problem constants (B=4, N=512, D_in=512, D_out=256), fp32 in/out.
constexpr int Bq   = 4;
constexpr int Nq   = 512;
constexpr int DIN  = 512;
constexpr int DOUT = 256;

__device__ __forceinline__ void fma4(float4& acc, const float s, const float4 v) {
    acc.x = __builtin_fmaf(s, v.x, acc.x);
    acc.y = __builtin_fmaf(s, v.y, acc.y);
    acc.z = __builtin_fmaf(s, v.z, acc.z);
    acc.w = __builtin_fmaf(s, v.w, acc.w);
}

// ---------------------------------------------------------------------------
// K0: WT[k][o] = W[o][k]  (512x256 <- 256x512), LDS tile transpose.
// ---------------------------------------------------------------------------
__global__ __launch_bounds__(256) void k0_wt(const float* __restrict__ W,
                                             float* __restrict__ WT) {
    __shared__ float tile[32][33];
    const int k0 = blockIdx.x * 32;
    const int o0 = blockIdx.y * 32;
    const int tx = threadIdx.x;       // 32
    const int ty = threadIdx.y;       // 8
#pragma unroll
    for (int j = 0; j < 4; ++j)
        tile[ty + 8 * j][tx] = W[(o0 + ty + 8 * j) * DIN + k0 + tx];
    __syncthreads();
#pragma unroll
    for (int j = 0; j < 4; ++j)
        WT[(k0 + ty + 8 * j) * DOUT + o0 + tx] = tile[tx][ty + 8 * j];
}

// ---------------------------------------------------------------------------
// K1: Wh = H @ WT (+ WhT + r = Wh.a). Grid 512 = (b, 4 n-rows), 1024 threads
// -> 2 blocks/CU, 8 waves/SIMD (max occupancy). Thread = (k-phase p = t>>7,
// o-pair od = t&127). Stream: WT float2, 32-deep batched prefetch
// (load16/compute16 interleave). H rows staged in LDS (8 KB), read as
// same-address b128 broadcasts (bandwidth-free). Phase partials: 32 KB LDS.
// ---------------------------------------------------------------------------
__global__ __launch_bounds__(1024, 4) void k1_wh(const float* __restrict__ H,
                                                 const float* __restrict__ WT,
                                                 const float* __restrict__ a,
                                                 float* __restrict__ Wh,
                                                 float* __restrict__ WhT,
                                                 float* __restrict__ r) {
    const int t   = threadIdx.x;
    const int blk = blockIdx.x;           // 512
    const int b   = blk & 3;              // XCD-swizzled batch
    const int n0  = (blk >> 2) << 2;      // 4 rows per block
    const int p   = __builtin_amdgcn_readfirstlane(t >> 7);  // k-phase 0..7 (64 k)
    const int od  = t & 127;              // o-pair {2od, 2od+1}

    __shared__ float  sH[4 * 512];        // 8 KB (H rows)
    __shared__ float2 sPart[8][4][128];   // 32 KB (phase partials)

    if (t < 512) {                        // stage H rows once (coalesced)
        const float4* src = (const float4*)(H + ((size_t)(b * Nq) + n0) * DIN);
        ((float4*)sH)[t] = src[t];
    }
    __syncthreads();

    const float2* __restrict__ wt2 = (const float2*)WT + od;   // [k]*128

    float2 acc[4];
#pragma unroll
    for (int rr = 0; rr < 4; ++rr) acc[rr] = make_float2(0.f, 0.f);

    const int k0 = p * 64;                // this phase's 64-k chunk
    float2 cA[16], cB[16];

#define K1_LOAD16(buf, kb)                                                  \
    _Pragma("unroll") for (int s = 0; s < 16; ++s) buf[s] = wt2[((kb) + s) * 128];

#define K1_COMP16(buf, kb)                                                  \
    _Pragma("unroll") for (int kq = 0; kq < 4; ++kq) {                      \
        _Pragma("unroll") for (int rr = 0; rr < 4; ++rr) {                  \
            const float4 h4 = *(const float4*)&sH[rr * 512 + (kb) + kq * 4];\
            _Pragma("unroll") for (int x = 0; x < 4; ++x) {                 \
                const float hk = ((const float*)&h4)[x];                    \
                const float2 wv = buf[kq * 4 + x];                          \
                acc[rr].x = __builtin_fmaf(hk, wv.x, acc[rr].x);            \
                acc[rr].y = __builtin_fmaf(hk, wv.y, acc[rr].y);            \
            }                                                               \
        }                                                                   \
    }

    K1_LOAD16(cA, k0)
    K1_LOAD16(cB, k0 + 16)
    K1_COMP16(cA, k0)
    K1_LOAD16(cA, k0 + 32)
    K1_COMP16(cB, k0 + 16)
    K1_LOAD16(cB, k0 + 48)
    K1_COMP16(cA, k0 + 32)
    K1_COMP16(cB, k0 + 48)
#undef K1_LOAD16
#undef K1_COMP16

#pragma unroll
    for (int rr = 0; rr < 4; ++rr) sPart[p][rr][od] = acc[rr];
    __syncthreads();

    const int w = __builtin_amdgcn_readfirstlane(t >> 6);   // wave 0..15
    if (w < 4) {                          // waves 0..3: one row each
        const int g  = w;
        const int oq = t & 63;            // o-quad
        float4 fin = make_float4(0.f, 0.f, 0.f, 0.f);
#pragma unroll
        for (int pp = 0; pp < 8; ++pp) {
            const float2 u = sPart[pp][g][2 * oq];
            const float2 v = sPart[pp][g][2 * oq + 1];
            fin.x += u.x; fin.y += u.y; fin.z += v.x; fin.w += v.y;
        }

        ((float4*)(Wh + ((size_t)(b * Nq) + n0 + g) * DOUT))[oq] = fin;

        float* wT = WhT + (size_t)b * DOUT * Nq;
        wT[(4 * oq + 0) * Nq + n0 + g] = fin.x;
        wT[(4 * oq + 1) * Nq + n0 + g] = fin.y;
        wT[(4 * oq + 2) * Nq + n0 + g] = fin.z;
        wT[(4 * oq + 3) * Nq + n0 + g] = fin.w;

        const float4 a4 = ((const float4*)a)[oq];
        float rp = a4.x * fin.x + a4.y * fin.y + a4.z * fin.z + a4.w * fin.w;
#pragma unroll
        for (int off = 32; off > 0; off >>= 1) rp += __shfl_xor(rp, off);
        if ((t & 63) == 0) r[(size_t)b * Nq + n0 + g] = rp;
    }
}

// ---------------------------------------------------------------------------
// K23: fused e+softmax (phase A) and out = P @ Wh (phase B).
// Block = (b, 8 i-rows), 1024 threads. Phase A: quarter q = t>>8 owns 64 o,
// thread owns j-pair; stream = WhT float2 with 32-deep batched prefetch;
// inner op = v_add + v_fma(|.|) = exactly 2 VALU/elem (abs is a free VOP3
// input modifier; NO packed max exists for fp32). Uniforms stay global
// s_loads (R8: LDS-staging them spills). P never touches global (sP).
// ---------------------------------------------------------------------------
__global__ __launch_bounds__(1024, 4) void k23(const float* __restrict__ Wh,
                                               const float* __restrict__ WhT,
                                               const float* __restrict__ a,
                                               const float* __restrict__ r,
                                               float* __restrict__ out) {
    const int t   = threadIdx.x;
    const int blk = blockIdx.x;           // 256
    const int b   = blk & 3;
    const int i0  = (blk >> 2) << 3;

    __shared__ float smem[8192];          // 32 KB arena: sAb (A) / sPart (B)
    __shared__ float sP[8 * 512];         // 16 KB (normalized P)
    __shared__ float wred[2][8][4];

    // ======================= Phase A: e + softmax -> sP ====================
    {
        const int q  = __builtin_amdgcn_readfirstlane(t >> 8);  // o-quarter
        const int jp = t & 255;            // j-pair {2jp, 2jp+1}
        const int obase = q * 64;

        const float2* __restrict__ wj2 =
            (const float2*)(WhT + (size_t)b * DOUT * Nq + (size_t)obase * Nq) + jp;
        const float* __restrict__ gwi = Wh + ((size_t)b * Nq + i0) * DOUT; // uniform
        const float* __restrict__ gr  = r + (size_t)b * Nq;

        float2 ab[8];
#pragma unroll
        for (int rr = 0; rr < 8; ++rr) ab[rr] = make_float2(0.f, 0.f);
        float2 cA[16], cB[16];

#define K2_LOAD16(buf, ob)                                                  \
    _Pragma("unroll") for (int s = 0; s < 16; ++s) buf[s] = wj2[((ob) + s) * 256];

#define K2_COMP16(buf, ob)                                                  \
    _Pragma("unroll") for (int og = 0; og < 4; ++og) {                      \
        const int o4 = obase + (ob) + og * 4;                               \
        const float4 a4 = *(const float4*)(a + o4);               /*s_load*/\
        _Pragma("unroll") for (int rr = 0; rr < 8; ++rr) {                  \
            const float4 wi4 = *(const float4*)(gwi + rr * DOUT + o4);      \
            _Pragma("unroll") for (int x = 0; x < 4; ++x) {                 \
                const float aq = ((const float*)&a4)[x];                    \
                const float wi = ((const float*)&wi4)[x];                   \
                const float2 wv = buf[og * 4 + x];                          \
                ab[rr].x = __builtin_fmaf(aq, __builtin_fabsf(wi + wv.x), ab[rr].x); \
                ab[rr].y = __builtin_fmaf(aq, __builtin_fabsf(wi + wv.y), ab[rr].y); \
            }                                                               \
        }                                                                   \
    }

        K2_LOAD16(cA, 0)
        K2_LOAD16(cB, 16)
        K2_COMP16(cA, 0)
        K2_LOAD16(cA, 32)
        K2_COMP16(cB, 16)
        K2_LOAD16(cB, 48)
        K2_COMP16(cA, 32)
        K2_COMP16(cB, 48)
#undef K2_LOAD16
#undef K2_COMP16

        // two-step quarter combine in the 32 KB arena: sAb[2][8][512]
        float2* sAb = (float2*)smem;       // (g*8+rr)*256 + jp
        if (q >= 2) {
#pragma unroll
            for (int rr = 0; rr < 8; ++rr) sAb[((q - 2) * 8 + rr) * 256 + jp] = ab[rr];
        }
        __syncthreads();
        if (q < 2) {
#pragma unroll
            for (int rr = 0; rr < 8; ++rr) {
                const float2 x = sAb[(q * 8 + rr) * 256 + jp];
                ab[rr].x += x.x; ab[rr].y += x.y;
            }
        }
        __syncthreads();
        if (q == 1) {
#pragma unroll
            for (int rr = 0; rr < 8; ++rr) sAb[(0 * 8 + rr) * 256 + jp] = ab[rr];
        }
        __syncthreads();

        float e0[8], e1[8];
        if (q == 0) {
            const float2 rj2 = ((const float2*)gr)[jp];   // coalesced
#pragma unroll
            for (int rr = 0; rr < 8; ++rr) {
                const float2 x = sAb[(0 * 8 + rr) * 256 + jp];
                const float A0 = ab[rr].x + x.x;
                const float A1 = ab[rr].y + x.y;
                const float ri = gr[i0 + rr];             // s_load
                e0[rr] = 0.6f * (ri + rj2.x) + 0.4f * A0;
                e1[rr] = 0.6f * (ri + rj2.y) + 0.4f * A1;
            }
        }

        const int lane = t & 63;
        const int w    = (t >> 6) & 3;     // wave within quarter

#pragma unroll
        for (int rr = 0; rr < 8; ++rr) {
            float v = (q == 0) ? fmaxf(e0[rr], e1[rr]) : -3e38f;
#pragma unroll
            for (int off = 32; off > 0; off >>= 1) v = fmaxf(v, __shfl_xor(v, off));
            if (lane == 0 && q == 0) wred[0][rr][w] = v;
        }
        __syncthreads();

        float p0[8], p1[8];
        if (q == 0) {
#pragma unroll
            for (int rr = 0; rr < 8; ++rr) {
                const float4 qv = *(const float4*)&wred[0][rr][0];
                const float m = fmaxf(fmaxf(qv.x, qv.y), fmaxf(qv.z, qv.w));
                p0[rr] = __expf(e0[rr] - m);
                p1[rr] = __expf(e1[rr] - m);
            }
        }
#pragma unroll
        for (int rr = 0; rr < 8; ++rr) {
            float v = (q == 0) ? (p0[rr] + p1[rr]) : 0.f;
#pragma unroll
            for (int off = 32; off > 0; off >>= 1) v += __shfl_xor(v, off);
            if (lane == 0 && q == 0) wred[1][rr][w] = v;
        }
        __syncthreads();

        if (q == 0) {
#pragma unroll
            for (int rr = 0; rr < 8; ++rr) {
                const float4 qv = *(const float4*)&wred[1][rr][0];
                const float inv = 1.0f / (qv.x + qv.y + qv.z + qv.w);
                ((float2*)sP)[rr * 256 + jp] = make_float2(p0[rr] * inv, p1[rr] * inv);
            }
        }
        __syncthreads();                  // sP ready; arena free for phase B
    }

    // ======================= Phase B: out = P @ Wh =========================
    {
        const int p2 = __builtin_amdgcn_readfirstlane(t >> 6);  // 0..15
        const int jh = p2 & 7;            // j-octant (64 j)
        const int rh = p2 >> 3;           // row-half (rows rh*4..rh*4+3)
        const int oq = t & 63;            // o-quad

        const float4* __restrict__ wh4 = (const float4*)(Wh + (size_t)b * Nq * DOUT) + oq;

        float4 acc[4];
#pragma unroll
        for (int rr = 0; rr < 4; ++rr) acc[rr] = make_float4(0.f, 0.f, 0.f, 0.f);

        const int j0 = jh * 64;
        float4 bufA[4], bufB[4];
#pragma unroll
        for (int s = 0; s < 4; ++s) bufA[s] = wh4[(j0 + s) * 64];

        for (int it = 0; it < 8; ++it) {  // 8 j per it
            const int jA = j0 + it * 8, jB = jA + 4;
#pragma unroll
            for (int s = 0; s < 4; ++s) bufB[s] = wh4[(jB + s) * 64];
#pragma unroll
            for (int rr = 0; rr < 4; ++rr) {
                const float4 p4 = *(const float4*)&sP[(rh * 4 + rr) * 512 + jA];
                fma4(acc[rr], p4.x, bufA[0]); fma4(acc[rr], p4.y, bufA[1]);
                fma4(acc[rr], p4.z, bufA[2]); fma4(acc[rr], p4.w, bufA[3]);
            }
            if (it < 7) {
#pragma unroll
                for (int s = 0; s < 4; ++s) bufA[s] = wh4[(jA + 8 + s) * 64];
            }
#pragma unroll
            for (int rr = 0; rr < 4; ++rr) {
                const float4 p4 = *(const float4*)&sP[(rh * 4 + rr) * 512 + jB];
                fma4(acc[rr], p4.x, bufB[0]); fma4(acc[rr], p4.y, bufB[1]);
                fma4(acc[rr], p4.z, bufB[2]); fma4(acc[rr], p4.w, bufB[3]);
            }
        }

        // two-step j-octant reduce in the arena: sPart[4][8][64] float4
        float4* sPart = (float4*)smem;
        if (jh < 4) {
#pragma unroll
            for (int rr = 0; rr < 4; ++rr)
                sPart[(jh * 8 + rh * 4 + rr) * 64 + oq] = acc[rr];
        }
        __syncthreads();
        if (jh >= 4) {
#pragma unroll
            for (int rr = 0; rr < 4; ++rr) {
                float4* d = &sPart[((jh - 4) * 8 + rh * 4 + rr) * 64 + oq];
                d->x += acc[rr].x; d->y += acc[rr].y;
                d->z += acc[rr].z; d->w += acc[rr].w;
            }
        }
        __syncthreads();

        if (p2 < 8) {                     // waves 0..7: one row each
            const int row = p2;
            const float4 f0 = sPart[(0 * 8 + row) * 64 + oq];
            const float4 f1 = sPart[(1 * 8 + row) * 64 + oq];
            const float4 f2 = sPart[(2 * 8 + row) * 64 + oq];
            const float4 f3 = sPart[(3 * 8 + row) * 64 + oq];
            float4 fin;
            fin.x = f0.x + f1.x + f2.x + f3.x;
            fin.y = f0.y + f1.y + f2.y + f3.y;
            fin.z = f0.z + f1.z + f2.z + f3.z;
            fin.w = f0.w + f1.w + f2.w + f3.w;
            ((float4*)(out + ((size_t)(b * Nq) + i0 + row) * DOUT))[oq] = fin;
        }
    }
}

// ---------------------------------------------------------------------------
extern "C" void kernel_launch(void* const* d_in, const int* in_sizes, int n_in,
                              void* d_out, int out_size, void* d_ws, size_t ws_size,
                              hipStream_t stream) {
    const float* H = (const float*)d_in[0];   // [4,512,512]
    const float* W = (const float*)d_in[1];   // [256,512]
    const float* a = (const float*)d_in[2];   // [256,1]
    float* out = (float*)d_out;               // [4,512,256]

    float* Wh  = (float*)d_ws;                 // 2 MB
    float* WhT = Wh  + Bq * Nq * DOUT;         // 2 MB
    float* r   = WhT + Bq * Nq * DOUT;         // 8 KB
    float* WT  = r   + Bq * Nq;                // 0.5 MB

    hipLaunchKernelGGL(k0_wt, dim3(16, 8), dim3(32, 8), 0, stream, W, WT);
    hipLaunchKernelGGL(k1_wh, dim3(512),   dim3(1024), 0, stream, H, WT, a, Wh, WhT, r);
    hipLaunchKernelGGL(k23,   dim3(256),   dim3(1024), 0, stream, Wh, WhT, a, r, out);
}

// Round 12
// 107.433 us; speedup vs baseline: 1.1223x; 1.1223x over previous
//
#include <hip/hip_runtime.h>

// Problem constants (B=4, N=512, D_in=512, D_out=256), fp32 in/out.
constexpr int Bq   = 4;
constexpr int Nq   = 512;
constexpr int DIN  = 512;
constexpr int DOUT = 256;

typedef _Float16 h2  __attribute__((ext_vector_type(2)));
typedef float    v2f __attribute__((ext_vector_type(2)));

#if defined(__has_builtin) && __has_builtin(__builtin_amdgcn_fdot2)
__device__ __forceinline__ float fdot2f(h2 a, h2 b, float c) {
    return __builtin_amdgcn_fdot2(a, b, c, false);   // v_dot2_f32_f16
}
#else
__device__ __forceinline__ float fdot2f(h2 a, h2 b, float c) {
    return (float)a.x * (float)b.x + (float)a.y * (float)b.y + c;
}
#endif

// ---------------------------------------------------------------------------
// K0: convert+pack inputs to fp16.
//   blocks 0..63     : WT16p[k2][o] = half2(W[o][2k2], W[o][2k2+1])  (LDS tile)
//   blocks 64..2111  : H16[n][k2]   = half2(H[n][2k2], H[n][2k2+1])  (copy)
//   block  2112      : a16[o2]      = half2(a[2o2], a[2o2+1])
// ---------------------------------------------------------------------------
__global__ __launch_bounds__(256) void k0_cvt(const float* __restrict__ W,
                                              const float* __restrict__ H,
                                              const float* __restrict__ a,
                                              h2* __restrict__ WT16p,
                                              h2* __restrict__ H16,
                                              h2* __restrict__ a16) {
    const int bid = blockIdx.x;
    const int t   = threadIdx.x;
    if (bid < 64) {
        __shared__ h2 tile[32][33];
        const int bx = bid & 7, by = bid >> 3;
        const int k20 = bx * 32, o0 = by * 32;
        const int tx = t & 31, ty = t >> 5;     // 32 x 8
#pragma unroll
        for (int jj = 0; jj < 4; ++jj) {
            const int o = o0 + ty + 8 * jj;
            const float2 v = *(const float2*)&W[o * DIN + 2 * (k20 + tx)];
            h2 hv; hv.x = (_Float16)v.x; hv.y = (_Float16)v.y;
            tile[tx][ty + 8 * jj] = hv;
        }
        __syncthreads();
#pragma unroll
        for (int jj = 0; jj < 4; ++jj) {
            const int k2g = k20 + ty + 8 * jj;
            WT16p[k2g * 256 + o0 + tx] = tile[ty + 8 * jj][tx];
        }
    } else if (bid < 64 + 2048) {
        const int idx = (bid - 64) * 256 + t;   // over 2048*256 h2 of H16
        const float2 v = *(const float2*)&H[2 * (size_t)idx];
        h2 hv; hv.x = (_Float16)v.x; hv.y = (_Float16)v.y;
        H16[idx] = hv;
    } else if (t < 128) {
        const float2 v = *(const float2*)&a[2 * t];
        h2 hv; hv.x = (_Float16)v.x; hv.y = (_Float16)v.y;
        a16[t] = hv;
    }
}

// ---------------------------------------------------------------------------
// K1: Wh = H @ W^T via v_dot2_f32_f16 (+ Wh16, WhT16p, r). Grid 512 =
// (b, 4 n-rows), 1024 threads, launch_bounds(1024,8) -> 8 waves/SIMD.
// Thread = (k-phase p = t>>8 [64 k2 each], o = t&255). Stream: WT16p dwords,
// coalesced, 8-deep double-buffer. H pairs = uniform s_loads (global).
// 1 dot2 per (row, k-pair): 256 VALU per thread. Partials: 16 KB LDS.
// ---------------------------------------------------------------------------
__global__ __launch_bounds__(1024, 8) void k1_wh(const h2* __restrict__ H16,
                                                 const h2* __restrict__ WT16p,
                                                 const float* __restrict__ a,
                                                 float* __restrict__ Wh,
                                                 h2* __restrict__ Wh16,
                                                 h2* __restrict__ WhT16p,
                                                 float* __restrict__ r) {
    const int t   = threadIdx.x;
    const int blk = blockIdx.x;           // 512
    const int b   = blk & 3;              // XCD-swizzled batch
    const int n0  = (blk >> 2) << 2;      // 4 rows per block
    const int p   = __builtin_amdgcn_readfirstlane(t >> 8);  // k-phase 0..3
    const int o   = t & 255;

    __shared__ float sPart[4][4][256];    // 16 KB
    __shared__ float sRed[8];

    const h2* __restrict__ wtp   = WT16p + o;                       // + k2*256
    const h2* __restrict__ hbase = H16 + (size_t)(b * Nq + n0) * 256; // uniform

    float acc[4] = {0.f, 0.f, 0.f, 0.f};
    const int k0p = p * 64;               // this phase's 64 k2
    h2 cA[8], cB[8];

#define K1_L8(buf, kb)                                                      \
    _Pragma("unroll") for (int s = 0; s < 8; ++s)                           \
        buf[s] = wtp[(k0p + (kb) + s) * 256];

#define K1_C8(buf, kb)                                                      \
    _Pragma("unroll") for (int s = 0; s < 8; ++s) {                         \
        const int k2 = k0p + (kb) + s;                                      \
        _Pragma("unroll") for (int rr = 0; rr < 4; ++rr)                    \
            acc[rr] = fdot2f(hbase[rr * 256 + k2], buf[s], acc[rr]);        \
    }

    K1_L8(cA, 0)  K1_L8(cB, 8)
    K1_C8(cA, 0)  K1_L8(cA, 16)
    K1_C8(cB, 8)  K1_L8(cB, 24)
    K1_C8(cA, 16) K1_L8(cA, 32)
    K1_C8(cB, 24) K1_L8(cB, 40)
    K1_C8(cA, 32) K1_L8(cA, 48)
    K1_C8(cB, 40) K1_L8(cB, 56)
    K1_C8(cA, 48)
    K1_C8(cB, 56)
#undef K1_L8
#undef K1_C8

#pragma unroll
    for (int rr = 0; rr < 4; ++rr) sPart[p][rr][o] = acc[rr];
    __syncthreads();

    if (t < 512) {
        const int row = t >> 7, op = t & 127;   // o-pair (2op, 2op+1)
        float f0 = 0.f, f1 = 0.f;
#pragma unroll
        for (int pp = 0; pp < 4; ++pp) {
            f0 += sPart[pp][row][2 * op];
            f1 += sPart[pp][row][2 * op + 1];
        }
        const int n = b * Nq + n0 + row;
        *(float2*)&Wh[(size_t)n * DOUT + 2 * op] = make_float2(f0, f1);
        h2 hv; hv.x = (_Float16)f0; hv.y = (_Float16)f1;
        Wh16[(size_t)n * 128 + op] = hv;                       // [n][o2]
        WhT16p[(size_t)b * 65536 + op * 512 + (n0 + row)] = hv; // [b][o2][j]

        const float2 av = *(const float2*)&a[2 * op];
        float pr = av.x * f0 + av.y * f1;
#pragma unroll
        for (int off = 32; off > 0; off >>= 1) pr += __shfl_xor(pr, off);
        if ((t & 63) == 0) sRed[t >> 6] = pr;
    }
    __syncthreads();
    if (t < 4) r[(size_t)b * Nq + n0 + t] = sRed[2 * t] + sRed[2 * t + 1];
}

// ---------------------------------------------------------------------------
// K23: fused e+softmax (phase A, fp16 packed) and out = P @ Wh (phase B,
// pk_fma_f32). Grid 512 = (b, 4 i-rows), 1024 threads, 2 blocks/CU.
// Phase A: half h = t>>9 owns 64 o-pairs; j = t&511. Per (row, o2):
// pk_add + pk_max(w,-w) + v_dot2_f32_f16 = 3 instr / 2 elems, fp32 acc.
// Uniforms (a16, Wh16 rows, r_i) = global s_loads. P stays in LDS (fp32).
// ---------------------------------------------------------------------------
__global__ __launch_bounds__(1024, 8) void k23(const float* __restrict__ Wh,
                                               const h2* __restrict__ Wh16,
                                               const h2* __restrict__ WhT16p,
                                               const h2* __restrict__ a16,
                                               const float* __restrict__ r,
                                               float* __restrict__ out) {
    const int t   = threadIdx.x;
    const int blk = blockIdx.x;           // 512
    const int b   = blk & 3;
    const int i0  = (blk >> 2) << 2;      // 4 i-rows

    __shared__ float smem[8192];          // 32 KB arena: sAb (A) / sPart (B)
    __shared__ float sP[4 * 512];         // 8 KB (normalized P, fp32)
    __shared__ float wred[2][4][8];

    // ======================= Phase A: e + softmax -> sP ====================
    {
        const int h  = __builtin_amdgcn_readfirstlane(t >> 9);  // 0/1
        const int j  = t & 511;
        const int ob = h * 64;            // o2 base (64 o-pairs = 128 o)

        const h2* __restrict__ wjp = WhT16p + (size_t)b * 65536 + (size_t)ob * 512 + j;
        const h2* __restrict__ wip = Wh16 + (size_t)(b * Nq + i0) * 128;  // uniform
        const float* __restrict__ gr = r + (size_t)b * Nq;

        float ab[4] = {0.f, 0.f, 0.f, 0.f};
        h2 cA[8], cB[8];

#define K2_L8(buf, kb)                                                      \
    _Pragma("unroll") for (int s = 0; s < 8; ++s)                           \
        buf[s] = wjp[((kb) + s) * 512];

#define K2_C8(buf, kb)                                                      \
    _Pragma("unroll") for (int s = 0; s < 8; ++s) {                         \
        const int o2 = ob + (kb) + s;                                       \
        const h2 a2 = a16[o2];                                  /* s_load */\
        _Pragma("unroll") for (int rr = 0; rr < 4; ++rr) {                  \
            const h2 wi = wip[rr * 128 + o2];                   /* s_load */\
            h2 w  = buf[s] + wi;                                /* pk_add */\
            h2 aw = __builtin_elementwise_max(w, -w);           /* pk_max */\
            ab[rr] = fdot2f(a2, aw, ab[rr]);                    /* dot2   */\
        }                                                                   \
    }

        K2_L8(cA, 0)  K2_L8(cB, 8)
        K2_C8(cA, 0)  K2_L8(cA, 16)
        K2_C8(cB, 8)  K2_L8(cB, 24)
        K2_C8(cA, 16) K2_L8(cA, 32)
        K2_C8(cB, 24) K2_L8(cB, 40)
        K2_C8(cA, 32) K2_L8(cA, 48)
        K2_C8(cB, 40) K2_L8(cB, 56)
        K2_C8(cA, 48)
        K2_C8(cB, 56)
#undef K2_L8
#undef K2_C8

        // combine halves
        float* sAb = smem;                // [4][512]
        if (h == 1) {
#pragma unroll
            for (int rr = 0; rr < 4; ++rr) sAb[rr * 512 + j] = ab[rr];
        }
        __syncthreads();

        float e[4], pv[4];
        if (h == 0) {
            const float rj = gr[j];       // coalesced
#pragma unroll
            for (int rr = 0; rr < 4; ++rr) {
                const float A = ab[rr] + sAb[rr * 512 + j];
                e[rr] = 0.6f * (gr[i0 + rr] + rj) + 0.4f * A;   // gr[i0+rr] s_load
            }
        }

        const int lane = t & 63;
        const int w    = t >> 6;          // h0: waves 0..7

#pragma unroll
        for (int rr = 0; rr < 4; ++rr) {
            float v = (h == 0) ? e[rr] : -3e38f;
#pragma unroll
            for (int off = 32; off > 0; off >>= 1) v = fmaxf(v, __shfl_xor(v, off));
            if (lane == 0 && h == 0) wred[0][rr][w] = v;
        }
        __syncthreads();
        if (h == 0) {
#pragma unroll
            for (int rr = 0; rr < 4; ++rr) {
                const float4 q0 = *(const float4*)&wred[0][rr][0];
                const float4 q1 = *(const float4*)&wred[0][rr][4];
                const float m = fmaxf(fmaxf(fmaxf(q0.x, q0.y), fmaxf(q0.z, q0.w)),
                                      fmaxf(fmaxf(q1.x, q1.y), fmaxf(q1.z, q1.w)));
                pv[rr] = __expf(e[rr] - m);
            }
        }
#pragma unroll
        for (int rr = 0; rr < 4; ++rr) {
            float v = (h == 0) ? pv[rr] : 0.f;
#pragma unroll
            for (int off = 32; off > 0; off >>= 1) v += __shfl_xor(v, off);
            if (lane == 0 && h == 0) wred[1][rr][w] = v;
        }
        __syncthreads();
        if (h == 0) {
#pragma unroll
            for (int rr = 0; rr < 4; ++rr) {
                const float4 q0 = *(const float4*)&wred[1][rr][0];
                const float4 q1 = *(const float4*)&wred[1][rr][4];
                const float s = (q0.x + q0.y + q0.z + q0.w) + (q1.x + q1.y + q1.z + q1.w);
                sP[rr * 512 + j] = pv[rr] * (1.0f / s);
            }
        }
        __syncthreads();                  // sP ready; arena free for phase B
    }

    // ======================= Phase B: out = P @ Wh =========================
    {
        const int w16 = __builtin_amdgcn_readfirstlane(t >> 6);  // 0..15
        const int jh  = w16 & 7;          // j-octant (64 j)
        const int rh  = w16 >> 3;         // rows rh*2, rh*2+1
        const int oq  = t & 63;           // o-quad

        const float4* __restrict__ wh4 = (const float4*)(Wh + (size_t)b * Nq * DOUT) + oq;

        v2f accL[2] = {(v2f)0.f, (v2f)0.f};   // [row] o-pair lo
        v2f accH[2] = {(v2f)0.f, (v2f)0.f};   // [row] o-pair hi

        const int j0 = jh * 64;
        float4 bufA[4], bufB[4];
#pragma unroll
        for (int s = 0; s < 4; ++s) bufA[s] = wh4[(j0 + s) * 64];

        for (int it = 0; it < 8; ++it) {  // 8 j per it
            const int jA = j0 + it * 8, jB = jA + 4;
#pragma unroll
            for (int s = 0; s < 4; ++s) bufB[s] = wh4[(jB + s) * 64];
#pragma unroll
            for (int rr = 0; rr < 2; ++rr) {
                const float4 p4 = *(const float4*)&sP[(rh * 2 + rr) * 512 + jA];
#pragma unroll
                for (int x = 0; x < 4; ++x) {
                    const float pj = ((const float*)&p4)[x];
                    const v2f pj2 = pj;
                    const v2f wl = {bufA[x].x, bufA[x].y};
                    const v2f wh = {bufA[x].z, bufA[x].w};
                    accL[rr] = __builtin_elementwise_fma(pj2, wl, accL[rr]);
                    accH[rr] = __builtin_elementwise_fma(pj2, wh, accH[rr]);
                }
            }
            if (it < 7) {
#pragma unroll
                for (int s = 0; s < 4; ++s) bufA[s] = wh4[(jA + 8 + s) * 64];
            }
#pragma unroll
            for (int rr = 0; rr < 2; ++rr) {
                const float4 p4 = *(const float4*)&sP[(rh * 2 + rr) * 512 + jB];
#pragma unroll
                for (int x = 0; x < 4; ++x) {
                    const float pj = ((const float*)&p4)[x];
                    const v2f pj2 = pj;
                    const v2f wl = {bufB[x].x, bufB[x].y};
                    const v2f wh = {bufB[x].z, bufB[x].w};
                    accL[rr] = __builtin_elementwise_fma(pj2, wl, accL[rr]);
                    accH[rr] = __builtin_elementwise_fma(pj2, wh, accH[rr]);
                }
            }
        }

        // reduce octants in arena: sPart[8 jh][4 rows][64 oq] float4 = 32 KB
        float4* sPart = (float4*)smem;
#pragma unroll
        for (int rr = 0; rr < 2; ++rr) {
            const int row = rh * 2 + rr;
            float4 f;
            f.x = accL[rr].x; f.y = accL[rr].y; f.z = accH[rr].x; f.w = accH[rr].y;
            sPart[(jh * 4 + row) * 64 + oq] = f;
        }
        __syncthreads();

        if (t < 256) {
            const int row = t >> 6, oqq = t & 63;
            float4 fin = make_float4(0.f, 0.f, 0.f, 0.f);
#pragma unroll
            for (int j8 = 0; j8 < 8; ++j8) {
                const float4 v = sPart[(j8 * 4 + row) * 64 + oqq];
                fin.x += v.x; fin.y += v.y; fin.z += v.z; fin.w += v.w;
            }
            ((float4*)(out + ((size_t)(b * Nq) + i0 + row) * DOUT))[oqq] = fin;
        }
    }
}

// ---------------------------------------------------------------------------
extern "C" void kernel_launch(void* const* d_in, const int* in_sizes, int n_in,
                              void* d_out, int out_size, void* d_ws, size_t ws_size,
                              hipStream_t stream) {
    const float* H = (const float*)d_in[0];   // [4,512,512]
    const float* W = (const float*)d_in[1];   // [256,512]
    const float* a = (const float*)d_in[2];   // [256,1]
    float* out = (float*)d_out;               // [4,512,256]

    float* Wh    = (float*)d_ws;               // 524288 f   (2 MB)
    float* r     = Wh + 524288;                // 2048 f
    h2* H16      = (h2*)(r + 2048);            // 524288 h2  (2 MB)
    h2* Wh16     = H16 + 524288;               // 262144 h2  (1 MB)  [n][o2]
    h2* WhT16p   = Wh16 + 262144;              // 262144 h2  (1 MB)  [b][o2][j]
    h2* WT16p    = WhT16p + 262144;            // 65536 h2   (256 KB) [k2][o]
    h2* a16      = WT16p + 65536;              // 128 h2

    hipLaunchKernelGGL(k0_cvt, dim3(2113), dim3(256),  0, stream, W, H, a, WT16p, H16, a16);
    hipLaunchKernelGGL(k1_wh,  dim3(512),  dim3(1024), 0, stream, H16, WT16p, a, Wh, Wh16, WhT16p, r);
    hipLaunchKernelGGL(k23,    dim3(512),  dim3(1024), 0, stream, Wh, Wh16, WhT16p, a16, r, out);
}

// Round 13
// 106.522 us; speedup vs baseline: 1.1319x; 1.0086x over previous
//
#include <hip/hip_runtime.h>

// Problem constants (B=4, N=512, D_in=512, D_out=256), fp32 in/out.
constexpr int Bq   = 4;
constexpr int Nq   = 512;
constexpr int DIN  = 512;
constexpr int DOUT = 256;

typedef _Float16 h2  __attribute__((ext_vector_type(2)));
typedef _Float16 h8  __attribute__((ext_vector_type(8)));
typedef float    f4v __attribute__((ext_vector_type(4)));
typedef float    v2f __attribute__((ext_vector_type(2)));

#if defined(__has_builtin) && __has_builtin(__builtin_amdgcn_fdot2)
__device__ __forceinline__ float fdot2f(h2 a, h2 b, float c) {
    return __builtin_amdgcn_fdot2(a, b, c, false);   // v_dot2_f32_f16
}
#else
__device__ __forceinline__ float fdot2f(h2 a, h2 b, float c) {
    return (float)a.x * (float)b.x + (float)a.y * (float)b.y + c;
}
#endif

// ---------------------------------------------------------------------------
// K0: straight convert-copies to fp16 (no transpose needed anymore):
//   blocks 0..1023    : H16[n][k2]
//   blocks 1024..1151 : W16[o][k2]   (natural layout = MFMA B-operand)
//   block  1152       : a16[o2]
// ---------------------------------------------------------------------------
__global__ __launch_bounds__(256) void k0_cvt(const float* __restrict__ W,
                                              const float* __restrict__ H,
                                              const float* __restrict__ a,
                                              h2* __restrict__ W16,
                                              h2* __restrict__ H16,
                                              h2* __restrict__ a16) {
    const int bid = blockIdx.x;
    const int t   = threadIdx.x;
    if (bid < 1024) {
        const size_t idx = ((size_t)bid * 256 + t) * 2;    // h2 index (even)
        const float4 v = *(const float4*)&H[2 * idx];
        h2 h0; h0.x = (_Float16)v.x; h0.y = (_Float16)v.y;
        h2 h1; h1.x = (_Float16)v.z; h1.y = (_Float16)v.w;
        H16[idx] = h0; H16[idx + 1] = h1;
    } else if (bid < 1152) {
        const size_t idx = ((size_t)(bid - 1024) * 256 + t) * 2;
        const float4 v = *(const float4*)&W[2 * idx];
        h2 h0; h0.x = (_Float16)v.x; h0.y = (_Float16)v.y;
        h2 h1; h1.x = (_Float16)v.z; h1.y = (_Float16)v.w;
        W16[idx] = h0; W16[idx + 1] = h1;
    } else if (t < 64) {
        const int idx = 2 * t;
        const float4 v = *(const float4*)&a[2 * idx];
        h2 h0; h0.x = (_Float16)v.x; h0.y = (_Float16)v.y;
        h2 h1; h1.x = (_Float16)v.z; h1.y = (_Float16)v.w;
        a16[idx] = h0; a16[idx + 1] = h1;
    }
}

// ---------------------------------------------------------------------------
// K1: Wh = H @ W^T via MFMA 16x16x32 f16. Grid 512 x 256 thr (4 waves).
// Wave = one 16x16 output tile: mt = bid>>2 -> (b = mt&3, n0 = (mt>>2)*16);
// o0 = (bid&3)*64 + wave*16. K-loop: 16 mfma, A from H16 (lane m=col),
// B from W16 (lane n=col), both one dwordx4/lane/iter, depth-1 prefetch.
// Epilogue: Wh fp32 + Wh16[n][o2] + WhT16p[b][o2][j] (pack via shfl_xor 1).
// Fragment layouts per guide: A[m=lane&15][k=quad*8+j]; C col=lane&15,
// row=quad*4+reg. No LDS, no barriers.
// ---------------------------------------------------------------------------
__global__ __launch_bounds__(256) void k1_wh(const h2* __restrict__ H16,
                                             const h2* __restrict__ W16,
                                             float* __restrict__ Wh,
                                             h2* __restrict__ Wh16,
                                             h2* __restrict__ WhT16p) {
    const int t    = threadIdx.x;
    const int w    = t >> 6;
    const int lane = t & 63;
    const int bid  = blockIdx.x;          // 512
    const int mt   = bid >> 2;            // 0..127
    const int b    = mt & 3;              // XCD spread
    const int n0   = (mt >> 2) << 4;      // 0..496
    const int o0   = ((bid & 3) << 6) + (w << 4);
    const int quad = lane >> 4;
    const int col  = lane & 15;

    // A: lane reads H16 row (n0+col), k2 offset quad*4 (+kb*16)
    const h2* __restrict__ aPtr = H16 + ((size_t)(b * Nq + n0 + col) * 256) + quad * 4;
    // B: lane reads W16 row (o0+col), same k2 offsets
    const h2* __restrict__ bPtr = W16 + ((size_t)(o0 + col) * 256) + quad * 4;

    f4v acc = {0.f, 0.f, 0.f, 0.f};
    h8 a0 = *(const h8*)aPtr;
    h8 b0 = *(const h8*)bPtr;

#pragma unroll
    for (int kb = 0; kb < 16; ++kb) {
        h8 a1 = a0, b1 = b0;
        if (kb < 15) {
            a1 = *(const h8*)(aPtr + (kb + 1) * 16);
            b1 = *(const h8*)(bPtr + (kb + 1) * 16);
        }
        acc = __builtin_amdgcn_mfma_f32_16x16x32_f16(a0, b0, acc, 0, 0, 0);
        a0 = a1; b0 = b1;
    }

    const int rowb = b * Nq + n0 + quad * 4;   // global row of reg 0
#pragma unroll
    for (int reg = 0; reg < 4; ++reg) {
        const float v = acc[reg];
        Wh[(size_t)(rowb + reg) * DOUT + o0 + col] = v;
        const float vp = __shfl_xor(v, 1);     // partner o
        if ((col & 1) == 0) {
            h2 hv; hv.x = (_Float16)v; hv.y = (_Float16)vp;
            const int o2 = (o0 + col) >> 1;
            Wh16[(size_t)(rowb + reg) * 128 + o2] = hv;                    // [n][o2]
            WhT16p[(size_t)b * 65536 + (size_t)o2 * 512 + (n0 + quad * 4 + reg)] = hv;
        }
    }
}

// ---------------------------------------------------------------------------
// K23: fused e+softmax (phase A, fp16 packed + dot2) and out = P @ Wh
// (phase B, pk_fma_f32). Grid 512 = (b, 4 i-rows), 1024 threads.
// Phase A also computes r_j = a.Wh_j (one extra dot2/o2) and publishes the
// combined r in LDS — k1 no longer produces r. Uniforms (a16, Wh16 rows)
// stay global s_loads (R8: LDS-staging them spills).
// ---------------------------------------------------------------------------
__global__ __launch_bounds__(1024, 8) void k23(const float* __restrict__ Wh,
                                               const h2* __restrict__ Wh16,
                                               const h2* __restrict__ WhT16p,
                                               const h2* __restrict__ a16,
                                               float* __restrict__ out) {
    const int t   = threadIdx.x;
    const int blk = blockIdx.x;           // 512
    const int b   = blk & 3;
    const int i0  = (blk >> 2) << 2;      // 4 i-rows

    __shared__ float smem[8192];          // 32 KB arena: sAb/sR (A), sPart (B)
    __shared__ float sP[4 * 512];         // 8 KB (normalized P, fp32)
    __shared__ float wred[2][4][8];

    // ======================= Phase A: e + softmax -> sP ====================
    {
        const int h  = __builtin_amdgcn_readfirstlane(t >> 9);  // 0/1
        const int j  = t & 511;
        const int ob = h * 64;            // o2 base (64 o-pairs = 128 o)

        const h2* __restrict__ wjp = WhT16p + (size_t)b * 65536 + (size_t)ob * 512 + j;
        const h2* __restrict__ wip = Wh16 + (size_t)(b * Nq + i0) * 128;  // uniform

        float ab[4] = {0.f, 0.f, 0.f, 0.f};
        float rja = 0.f;                  // this half's partial of r_j
        h2 cA[8], cB[8];

#define K2_L8(buf, kb)                                                      \
    _Pragma("unroll") for (int s = 0; s < 8; ++s)                           \
        buf[s] = wjp[((kb) + s) * 512];

#define K2_C8(buf, kb)                                                      \
    _Pragma("unroll") for (int s = 0; s < 8; ++s) {                         \
        const int o2 = ob + (kb) + s;                                       \
        const h2 a2 = a16[o2];                                  /* s_load */\
        rja = fdot2f(a2, buf[s], rja);                                      \
        _Pragma("unroll") for (int rr = 0; rr < 4; ++rr) {                  \
            const h2 wi = wip[rr * 128 + o2];                   /* s_load */\
            h2 w  = buf[s] + wi;                                /* pk_add */\
            h2 aw = __builtin_elementwise_max(w, -w);           /* pk_max */\
            ab[rr] = fdot2f(a2, aw, ab[rr]);                    /* dot2   */\
        }                                                                   \
    }

        K2_L8(cA, 0)  K2_L8(cB, 8)
        K2_C8(cA, 0)  K2_L8(cA, 16)
        K2_C8(cB, 8)  K2_L8(cB, 24)
        K2_C8(cA, 16) K2_L8(cA, 32)
        K2_C8(cB, 24) K2_L8(cB, 40)
        K2_C8(cA, 32) K2_L8(cA, 48)
        K2_C8(cB, 40) K2_L8(cB, 56)
        K2_C8(cA, 48)
        K2_C8(cB, 56)
#undef K2_L8
#undef K2_C8

        // combine halves: sAb[4][512] @ smem[0..2047], sRh @ [2048..2559],
        // final r @ [2560..3071]
        float* sAb = smem;
        float* sRh = smem + 2048;
        float* sRf = smem + 2560;
        if (h == 1) {
#pragma unroll
            for (int rr = 0; rr < 4; ++rr) sAb[rr * 512 + j] = ab[rr];
            sRh[j] = rja;
        }
        __syncthreads();

        float rj = 0.f;
        if (h == 0) {
#pragma unroll
            for (int rr = 0; rr < 4; ++rr) ab[rr] += sAb[rr * 512 + j];
            rj = rja + sRh[j];
            sRf[j] = rj;
        }
        __syncthreads();                  // sRf visible to all

        float e[4], pv[4];
        if (h == 0) {
#pragma unroll
            for (int rr = 0; rr < 4; ++rr)
                e[rr] = 0.6f * (sRf[i0 + rr] + rj) + 0.4f * ab[rr];
        }

        const int lane = t & 63;
        const int w    = t >> 6;          // h0: waves 0..7

#pragma unroll
        for (int rr = 0; rr < 4; ++rr) {
            float v = (h == 0) ? e[rr] : -3e38f;
#pragma unroll
            for (int off = 32; off > 0; off >>= 1) v = fmaxf(v, __shfl_xor(v, off));
            if (lane == 0 && h == 0) wred[0][rr][w] = v;
        }
        __syncthreads();
        if (h == 0) {
#pragma unroll
            for (int rr = 0; rr < 4; ++rr) {
                const float4 q0 = *(const float4*)&wred[0][rr][0];
                const float4 q1 = *(const float4*)&wred[0][rr][4];
                const float m = fmaxf(fmaxf(fmaxf(q0.x, q0.y), fmaxf(q0.z, q0.w)),
                                      fmaxf(fmaxf(q1.x, q1.y), fmaxf(q1.z, q1.w)));
                pv[rr] = __expf(e[rr] - m);
            }
        }
#pragma unroll
        for (int rr = 0; rr < 4; ++rr) {
            float v = (h == 0) ? pv[rr] : 0.f;
#pragma unroll
            for (int off = 32; off > 0; off >>= 1) v += __shfl_xor(v, off);
            if (lane == 0 && h == 0) wred[1][rr][w] = v;
        }
        __syncthreads();
        if (h == 0) {
#pragma unroll
            for (int rr = 0; rr < 4; ++rr) {
                const float4 q0 = *(const float4*)&wred[1][rr][0];
                const float4 q1 = *(const float4*)&wred[1][rr][4];
                const float s = (q0.x + q0.y + q0.z + q0.w) + (q1.x + q1.y + q1.z + q1.w);
                sP[rr * 512 + j] = pv[rr] * (1.0f / s);
            }
        }
        __syncthreads();                  // sP ready; arena free for phase B
    }

    // ======================= Phase B: out = P @ Wh =========================
    {
        const int w16 = __builtin_amdgcn_readfirstlane(t >> 6);  // 0..15
        const int jh  = w16 & 7;          // j-octant (64 j)
        const int rh  = w16 >> 3;         // rows rh*2, rh*2+1
        const int oq  = t & 63;           // o-quad

        const float4* __restrict__ wh4 = (const float4*)(Wh + (size_t)b * Nq * DOUT) + oq;

        v2f accL[2] = {(v2f)0.f, (v2f)0.f};
        v2f accH[2] = {(v2f)0.f, (v2f)0.f};

        const int j0 = jh * 64;
        float4 bufA[4], bufB[4];
#pragma unroll
        for (int s = 0; s < 4; ++s) bufA[s] = wh4[(j0 + s) * 64];

        for (int it = 0; it < 8; ++it) {  // 8 j per it
            const int jA = j0 + it * 8, jB = jA + 4;
#pragma unroll
            for (int s = 0; s < 4; ++s) bufB[s] = wh4[(jB + s) * 64];
#pragma unroll
            for (int rr = 0; rr < 2; ++rr) {
                const float4 p4 = *(const float4*)&sP[(rh * 2 + rr) * 512 + jA];
#pragma unroll
                for (int x = 0; x < 4; ++x) {
                    const float pj = ((const float*)&p4)[x];
                    const v2f pj2 = pj;
                    const v2f wl = {bufA[x].x, bufA[x].y};
                    const v2f wh = {bufA[x].z, bufA[x].w};
                    accL[rr] = __builtin_elementwise_fma(pj2, wl, accL[rr]);
                    accH[rr] = __builtin_elementwise_fma(pj2, wh, accH[rr]);
                }
            }
            if (it < 7) {
#pragma unroll
                for (int s = 0; s < 4; ++s) bufA[s] = wh4[(jA + 8 + s) * 64];
            }
#pragma unroll
            for (int rr = 0; rr < 2; ++rr) {
                const float4 p4 = *(const float4*)&sP[(rh * 2 + rr) * 512 + jB];
#pragma unroll
                for (int x = 0; x < 4; ++x) {
                    const float pj = ((const float*)&p4)[x];
                    const v2f pj2 = pj;
                    const v2f wl = {bufB[x].x, bufB[x].y};
                    const v2f wh = {bufB[x].z, bufB[x].w};
                    accL[rr] = __builtin_elementwise_fma(pj2, wl, accL[rr]);
                    accH[rr] = __builtin_elementwise_fma(pj2, wh, accH[rr]);
                }
            }
        }

        float4* sPart = (float4*)smem;    // [8 jh][4 rows][64 oq] = 32 KB
#pragma unroll
        for (int rr = 0; rr < 2; ++rr) {
            const int row = rh * 2 + rr;
            float4 f;
            f.x = accL[rr].x; f.y = accL[rr].y; f.z = accH[rr].x; f.w = accH[rr].y;
            sPart[(jh * 4 + row) * 64 + oq] = f;
        }
        __syncthreads();

        if (t < 256) {
            const int row = t >> 6, oqq = t & 63;
            float4 fin = make_float4(0.f, 0.f, 0.f, 0.f);
#pragma unroll
            for (int j8 = 0; j8 < 8; ++j8) {
                const float4 v = sPart[(j8 * 4 + row) * 64 + oqq];
                fin.x += v.x; fin.y += v.y; fin.z += v.z; fin.w += v.w;
            }
            ((float4*)(out + ((size_t)(b * Nq) + i0 + row) * DOUT))[oqq] = fin;
        }
    }
}

// ---------------------------------------------------------------------------
extern "C" void kernel_launch(void* const* d_in, const int* in_sizes, int n_in,
                              void* d_out, int out_size, void* d_ws, size_t ws_size,
                              hipStream_t stream) {
    const float* H = (const float*)d_in[0];   // [4,512,512]
    const float* W = (const float*)d_in[1];   // [256,512]
    const float* a = (const float*)d_in[2];   // [256,1]
    float* out = (float*)d_out;               // [4,512,256]

    float* Wh  = (float*)d_ws;                 // 524288 f  (2 MB)
    h2* H16    = (h2*)(Wh + 524288);           // 524288 h2 (2 MB)   [n][k2]
    h2* Wh16   = H16 + 524288;                 // 262144 h2 (1 MB)   [n][o2]
    h2* WhT16p = Wh16 + 262144;                // 262144 h2 (1 MB)   [b][o2][j]
    h2* W16    = WhT16p + 262144;              // 65536 h2  (256 KB) [o][k2]
    h2* a16    = W16 + 65536;                  // 128 h2

    hipLaunchKernelGGL(k0_cvt, dim3(1153), dim3(256),  0, stream, W, H, a, W16, H16, a16);
    hipLaunchKernelGGL(k1_wh,  dim3(512),  dim3(256),  0, stream, H16, W16, Wh, Wh16, WhT16p);
    hipLaunchKernelGGL(k23,    dim3(512),  dim3(1024), 0, stream, Wh, Wh16, WhT16p, a16, out);
}